// Round 20
// baseline (159.672 us; speedup 1.0000x reference)
//
#include <hip/hip_runtime.h>
#include <hip/hip_bf16.h>
#include <math.h>

// out[b,f,t] = sum_l sig[b,l] * win[t,l] * cos(2*pi*fv[f]*l/8192)
// R20 = R17 with an 8x IDEMPOTENT REPEAT inside the kernel: a counter-
// visibility probe. The kernel grows to ~118 us -> rises above the harness's
// 40 us ws-poison fills into the profile top-5, giving the FIRST direct
// MfmaUtil/VALUBusy read of this kernel family. Implied-clock math then
// discriminates latency-bound-at-2.4GHz (VALUBusy ~20%) from DVFS-capped
// (~600-900 MHz -> VALUBusy 60-90%).  Each pass re-stages sig (the reduce
// phase clobbers the LDS union) and rewrites the same output (idempotent).
// fv/tc = linspace->int32 reproduced exactly in fp32 (R0-verified).
// 32x32 C/D layout: col=lane&31, row=(reg&3)+8*(reg>>2)+4*(lane>>5).

#define L_ 8192
#define B_ 32
#define REPS 8

typedef _Float16 half8 __attribute__((ext_vector_type(8)));
typedef __fp16 fp16x2 __attribute__((ext_vector_type(2)));
typedef float float2v __attribute__((ext_vector_type(2)));
typedef float float4v __attribute__((ext_vector_type(4)));
typedef float float16v __attribute__((ext_vector_type(16)));

#define H_ 0.001220703125f                 // 1/819.2 = 5/4096 (exact)
#define CSTEP_ 7.66990393942594528198e-4f  // 2*pi/8192
#define DLT_ 0.01953125f                   // 16*H (exact)
#define DLT2H_ 1.9073486328125e-4f         // (16*H)^2 / 2 (exact)
#define Q16_ 0.99961860303f                // exp(-(16*H)^2)

__global__ __launch_bounds__(512, 2) void gabor_kernel(
    const float* __restrict__ signal, float* __restrict__ out) {
  const int bx = blockIdx.x;  // 256 = bp16 * th4 * fh4
  const int bp = bx & 15;     // b-pair: b = 2*bp, 2*bp+1
  const int th = (bx >> 4) & 3;
  const int fh = (bx >> 6) & 3;
  const int tid = threadIdx.x;  // 512
  const int lane = tid & 63;
  const int wv = tid >> 6;      // 0..7
  const int row32 = lane & 31;  // A row (t) and B col (f) for this lane
  const int kg = lane >> 5;     // k subgroup (0/1) within K=16

  // LDS union: Sg lives during the K-loop, Acc (reduction) after it.
  __shared__ __align__(16) char smraw[32768];
  _Float16(*Sg)[L_] = (_Float16(*)[L_])smraw;       // [2][8192] f16, 32 KB
  float4v(*Acc)[64][4] = (float4v(*)[64][4])smraw;  // [8][64][4], 32 KB

  const int t0 = th * 32;
  const int f0 = fh * 32;
  const int k0 = wv * 1024 + kg * 8;  // element j=0 at step 0; +16 per step
  const float2v Q16v = {Q16_, Q16_};

  union H8 { fp16x2 h2[4]; half8 h8; };

#pragma unroll 1
  for (int rep = 0; rep < REPS; ++rep) {
    // ---- stage sig rows 2bp, 2bp+1 (re-done each pass: reduce clobbers) --
    __syncthreads();  // prior pass's Acc reads complete before overwrite
#pragma unroll
    for (int bi = 0; bi < 2; ++bi) {
      const float* srow = signal + (size_t)(2 * bp + bi) * L_;
#pragma unroll
      for (int i = 0; i < 2; ++i) {
        const int off = i * 4096 + tid * 8;
        float4v s0 = *(const float4v*)(srow + off);
        float4v s1 = *(const float4v*)(srow + off + 4);
        union { fp16x2 h2[4]; half8 h8; } sh;
        sh.h2[0] = __builtin_amdgcn_cvt_pkrtz(s0[0], s0[1]);
        sh.h2[1] = __builtin_amdgcn_cvt_pkrtz(s0[2], s0[3]);
        sh.h2[2] = __builtin_amdgcn_cvt_pkrtz(s1[0], s1[1]);
        sh.h2[3] = __builtin_amdgcn_cvt_pkrtz(s1[2], s1[3]);
        *(half8*)&Sg[bi][off] = sh.h8;
      }
    }
    __syncthreads();

    // ---- per-lane fragment state (re-seeded each pass) ----
    float2v w2[4], Rw2[4];   // Gaussian value + step-ratio (8 els)
    float2v cE2[4], cO2[4];  // Chebyshev ping-pong (8 els)
    float2v K16v;
    {
      const float tc =
          truncf((float)(t0 + row32) * (8191.0f / 127.0f));
      const int fv = (int)((float)(f0 + row32) * (4096.0f / 127.0f));
      const float K16 = 2.0f * __cosf((float)((fv * 16) & (L_ - 1)) * CSTEP_);
      K16v = (float2v){K16, K16};
#pragma unroll
      for (int q = 0; q < 4; ++q) {
#pragma unroll
        for (int h = 0; h < 2; ++h) {
          const int j = 2 * q + h;
          const float x = ((float)(k0 + j) - tc) * H_;
          w2[q][h] = __expf(-0.5f * x * x);
          Rw2[q][h] = __expf(__builtin_fmaf(-DLT_, x, -DLT2H_));
          cE2[q][h] = __cosf((float)((fv * (k0 + j)) & (L_ - 1)) * CSTEP_);
          cO2[q][h] =
              __cosf((float)((fv * (k0 + j + 8176)) & (L_ - 1)) * CSTEP_);
        }
      }
    }

    float16v acc[2];
    acc[0] = (float16v)(0.0f);
    acc[1] = (float16v)(0.0f);

    // ---- 64 K-steps: 32 rolled iterations x 2 ping-pong, sig prefetched --
    half8 curE0 = *(const half8*)&Sg[0][k0];
    half8 curE1 = *(const half8*)&Sg[1][k0];
    half8 curO0 = *(const half8*)&Sg[0][k0 + 16];
    half8 curO1 = *(const half8*)&Sg[1][k0 + 16];

#pragma unroll 1
    for (int p = 0; p < 32; ++p) {
      const int kn = k0 + ((p + 1) & 31) * 32;
      half8 nxtE0 = *(const half8*)&Sg[0][kn];
      half8 nxtE1 = *(const half8*)&Sg[1][kn];
      half8 nxtO0 = *(const half8*)&Sg[0][kn + 16];
      half8 nxtO1 = *(const half8*)&Sg[1][kn + 16];

      {
        H8 ha, hc;
#pragma unroll
        for (int q = 0; q < 4; ++q) {
          ha.h2[q] = __builtin_amdgcn_cvt_pkrtz(w2[q][0], w2[q][1]);
          hc.h2[q] = __builtin_amdgcn_cvt_pkrtz(cE2[q][0], cE2[q][1]);
        }
#pragma unroll
        for (int q = 0; q < 4; ++q) {
          w2[q] *= Rw2[q];
          Rw2[q] *= Q16v;
          cO2[q] = __builtin_elementwise_fma(K16v, cE2[q], -cO2[q]);
        }
        acc[0] = __builtin_amdgcn_mfma_f32_32x32x16_f16(ha.h8, hc.h8 * curE0,
                                                        acc[0], 0, 0, 0);
        acc[1] = __builtin_amdgcn_mfma_f32_32x32x16_f16(ha.h8, hc.h8 * curE1,
                                                        acc[1], 0, 0, 0);
      }
      {
        H8 ha, hc;
#pragma unroll
        for (int q = 0; q < 4; ++q) {
          ha.h2[q] = __builtin_amdgcn_cvt_pkrtz(w2[q][0], w2[q][1]);
          hc.h2[q] = __builtin_amdgcn_cvt_pkrtz(cO2[q][0], cO2[q][1]);
        }
#pragma unroll
        for (int q = 0; q < 4; ++q) {
          w2[q] *= Rw2[q];
          Rw2[q] *= Q16v;
          cE2[q] = __builtin_elementwise_fma(K16v, cO2[q], -cE2[q]);
        }
        acc[0] = __builtin_amdgcn_mfma_f32_32x32x16_f16(ha.h8, hc.h8 * curO0,
                                                        acc[0], 0, 0, 0);
        acc[1] = __builtin_amdgcn_mfma_f32_32x32x16_f16(ha.h8, hc.h8 * curO1,
                                                        acc[1], 0, 0, 0);
      }
      curE0 = nxtE0;
      curE1 = nxtE1;
      curO0 = nxtO0;
      curO1 = nxtO1;
    }

    // ---- two-phase reduction through LDS (clobbers Sg space) ----
#pragma unroll
    for (int bi = 0; bi < 2; ++bi) {
      __syncthreads();
#pragma unroll
      for (int g = 0; g < 4; ++g) {
        float4v v = {acc[bi][4 * g], acc[bi][4 * g + 1], acc[bi][4 * g + 2],
                     acc[bi][4 * g + 3]};
        Acc[wv][lane][g] = v;
      }
      __syncthreads();
      if (wv < 4) {
        float4v sum = Acc[0][lane][wv];
#pragma unroll
        for (int w = 1; w < 8; ++w) sum += Acc[w][lane][wv];
        const int f = f0 + (lane & 31);
        const int t = t0 + 8 * wv + 4 * (lane >> 5);
        *(float4v*)(out + ((size_t)((2 * bp + bi) * 128 + f)) * 128 + t) = sum;
      }
    }
  }
}

extern "C" void kernel_launch(void* const* d_in, const int* in_sizes, int n_in,
                              void* d_out, int out_size, void* d_ws, size_t ws_size,
                              hipStream_t stream) {
  const float* signal = (const float*)d_in[0];
  float* out = (float*)d_out;
  gabor_kernel<<<dim3(256), dim3(512), 0, stream>>>(signal, out);
}

// Round 21
// 66.545 us; speedup vs baseline: 2.3995x; 2.3995x over previous
//
#include <hip/hip_runtime.h>
#include <hip/hip_bf16.h>
#include <math.h>

// out[b,f,t] = sum_l sig[b,l] * win[t,l] * cos(2*pi*fv[f]*l/8192)
// R21 = R17 (best: 67.6 us) + reduce-phase LDS bank-conflict fix:
// Acc padded [8][64][4] -> [8][64][5] (lane stride 64B -> 80B, 2 -> 8
// distinct banks, ~4x fewer conflicts; R20 counters: 4.7M conflict-cycles,
// ~2.9 us/CU, almost all in the reduce).
// R20 probe established: kernel is issue-bound (VALU 60% + MFMA 23%) at a
// DVFS-pinned ~800 MHz; dur = fill ~41 + fixed ~11.6 + kernel ~15.
// fv/tc = linspace->int32 reproduced exactly in fp32 (R0-verified).
// 32x32 C/D layout: col=lane&31, row=(reg&3)+8*(reg>>2)+4*(lane>>5).

#define L_ 8192
#define B_ 32

typedef _Float16 half8 __attribute__((ext_vector_type(8)));
typedef __fp16 fp16x2 __attribute__((ext_vector_type(2)));
typedef float float2v __attribute__((ext_vector_type(2)));
typedef float float4v __attribute__((ext_vector_type(4)));
typedef float float16v __attribute__((ext_vector_type(16)));

#define H_ 0.001220703125f                 // 1/819.2 = 5/4096 (exact)
#define CSTEP_ 7.66990393942594528198e-4f  // 2*pi/8192
#define DLT_ 0.01953125f                   // 16*H (exact)
#define DLT2H_ 1.9073486328125e-4f         // (16*H)^2 / 2 (exact)
#define Q16_ 0.99961860303f                // exp(-(16*H)^2)

__global__ __launch_bounds__(512, 2) void gabor_kernel(
    const float* __restrict__ signal, float* __restrict__ out) {
  const int bx = blockIdx.x;  // 256 = bp16 * th4 * fh4
  const int bp = bx & 15;     // b-pair: b = 2*bp, 2*bp+1
  const int th = (bx >> 4) & 3;
  const int fh = (bx >> 6) & 3;
  const int tid = threadIdx.x;  // 512
  const int lane = tid & 63;
  const int wv = tid >> 6;      // 0..7
  const int row32 = lane & 31;  // A row (t) and B col (f) for this lane
  const int kg = lane >> 5;     // k subgroup (0/1) within K=16

  // LDS union: Sg (32 KB) lives during the K-loop; Acc (40 KB, padded to
  // break reduce-phase bank conflicts) lives after it.
  __shared__ __align__(16) char smraw[40960];
  _Float16(*Sg)[L_] = (_Float16(*)[L_])smraw;       // [2][8192] f16, 32 KB
  float4v(*Acc)[64][5] = (float4v(*)[64][5])smraw;  // [8][64][5], 40 KB

  // ---- stage sig rows 2bp, 2bp+1 (once) ----
#pragma unroll
  for (int bi = 0; bi < 2; ++bi) {
    const float* srow = signal + (size_t)(2 * bp + bi) * L_;
#pragma unroll
    for (int i = 0; i < 2; ++i) {
      const int off = i * 4096 + tid * 8;
      float4v s0 = *(const float4v*)(srow + off);
      float4v s1 = *(const float4v*)(srow + off + 4);
      union { fp16x2 h2[4]; half8 h8; } sh;
      sh.h2[0] = __builtin_amdgcn_cvt_pkrtz(s0[0], s0[1]);
      sh.h2[1] = __builtin_amdgcn_cvt_pkrtz(s0[2], s0[3]);
      sh.h2[2] = __builtin_amdgcn_cvt_pkrtz(s1[0], s1[1]);
      sh.h2[3] = __builtin_amdgcn_cvt_pkrtz(s1[2], s1[3]);
      *(half8*)&Sg[bi][off] = sh.h8;
    }
  }
  __syncthreads();

  const int t0 = th * 32;
  const int f0 = fh * 32;
  const int k0 = wv * 1024 + kg * 8;  // element j=0 at step 0; +16 per step

  // ---- per-lane fragment state (packed f32 pairs), ONE t/f row per lane --
  float2v w2[4], Rw2[4];   // Gaussian value + step-ratio (8 els)
  float2v cE2[4], cO2[4];  // Chebyshev ping-pong (8 els)
  float2v K16v;
  const float2v Q16v = {Q16_, Q16_};
  {
    const float tc = truncf((float)(t0 + row32) * (8191.0f / 127.0f));
    const int fv = (int)((float)(f0 + row32) * (4096.0f / 127.0f));
    const float K16 = 2.0f * __cosf((float)((fv * 16) & (L_ - 1)) * CSTEP_);
    K16v = (float2v){K16, K16};
#pragma unroll
    for (int q = 0; q < 4; ++q) {
#pragma unroll
      for (int h = 0; h < 2; ++h) {
        const int j = 2 * q + h;
        const float x = ((float)(k0 + j) - tc) * H_;
        w2[q][h] = __expf(-0.5f * x * x);
        // ratio for k += 16: exp(-16*H*x - (16H)^2/2)
        Rw2[q][h] = __expf(__builtin_fmaf(-DLT_, x, -DLT2H_));
        cE2[q][h] = __cosf((float)((fv * (k0 + j)) & (L_ - 1)) * CSTEP_);
        // value at k-16 (k0+j+8176 == k0+j-16 mod 8192)
        cO2[q][h] =
            __cosf((float)((fv * (k0 + j + 8176)) & (L_ - 1)) * CSTEP_);
      }
    }
  }

  float16v acc[2];  // per b; 32 VGPRs total
  acc[0] = (float16v)(0.0f);
  acc[1] = (float16v)(0.0f);

  union H8 { fp16x2 h2[4]; half8 h8; };

  // ---- 64 K-steps (K=16): 32 rolled iterations x 2 ping-pong, with sig
  //      register prefetch one full iteration ahead ----
  half8 curE0 = *(const half8*)&Sg[0][k0];
  half8 curE1 = *(const half8*)&Sg[1][k0];
  half8 curO0 = *(const half8*)&Sg[0][k0 + 16];
  half8 curO1 = *(const half8*)&Sg[1][k0 + 16];

#pragma unroll 1
  for (int p = 0; p < 32; ++p) {
    // prefetch iteration p+1 (masked wrap avoids LDS OOB on last iter)
    const int kn = k0 + ((p + 1) & 31) * 32;
    half8 nxtE0 = *(const half8*)&Sg[0][kn];
    half8 nxtE1 = *(const half8*)&Sg[1][kn];
    half8 nxtO0 = *(const half8*)&Sg[0][kn + 16];
    half8 nxtO1 = *(const half8*)&Sg[1][kn + 16];

    // even sub-step: fragments from w2, cE2
    {
      H8 ha, hc;
#pragma unroll
      for (int q = 0; q < 4; ++q) {
        ha.h2[q] = __builtin_amdgcn_cvt_pkrtz(w2[q][0], w2[q][1]);
        hc.h2[q] = __builtin_amdgcn_cvt_pkrtz(cE2[q][0], cE2[q][1]);
      }
#pragma unroll
      for (int q = 0; q < 4; ++q) {
        w2[q] *= Rw2[q];
        Rw2[q] *= Q16v;
        cO2[q] = __builtin_elementwise_fma(K16v, cE2[q], -cO2[q]);
      }
      acc[0] = __builtin_amdgcn_mfma_f32_32x32x16_f16(ha.h8, hc.h8 * curE0,
                                                      acc[0], 0, 0, 0);
      acc[1] = __builtin_amdgcn_mfma_f32_32x32x16_f16(ha.h8, hc.h8 * curE1,
                                                      acc[1], 0, 0, 0);
    }
    // odd sub-step: fragments from w2 (advanced), cO2
    {
      H8 ha, hc;
#pragma unroll
      for (int q = 0; q < 4; ++q) {
        ha.h2[q] = __builtin_amdgcn_cvt_pkrtz(w2[q][0], w2[q][1]);
        hc.h2[q] = __builtin_amdgcn_cvt_pkrtz(cO2[q][0], cO2[q][1]);
      }
#pragma unroll
      for (int q = 0; q < 4; ++q) {
        w2[q] *= Rw2[q];
        Rw2[q] *= Q16v;
        cE2[q] = __builtin_elementwise_fma(K16v, cO2[q], -cE2[q]);
      }
      acc[0] = __builtin_amdgcn_mfma_f32_32x32x16_f16(ha.h8, hc.h8 * curO0,
                                                      acc[0], 0, 0, 0);
      acc[1] = __builtin_amdgcn_mfma_f32_32x32x16_f16(ha.h8, hc.h8 * curO1,
                                                      acc[1], 0, 0, 0);
    }
    curE0 = nxtE0;
    curE1 = nxtE1;
    curO0 = nxtO0;
    curO1 = nxtO1;
  }

  // ---- two-phase reduction through LDS (reusing Sg space, padded rows) --
  // 32x32 D frag: col(f)=lane&31, row(t)=(reg&3)+8*(reg>>2)+4*(lane>>5)
#pragma unroll
  for (int bi = 0; bi < 2; ++bi) {
    __syncthreads();  // previous LDS use complete
#pragma unroll
    for (int g = 0; g < 4; ++g) {
      float4v v = {acc[bi][4 * g], acc[bi][4 * g + 1], acc[bi][4 * g + 2],
                   acc[bi][4 * g + 3]};
      Acc[wv][lane][g] = v;
    }
    __syncthreads();
    if (wv < 4) {
      float4v sum = Acc[0][lane][wv];
#pragma unroll
      for (int w = 1; w < 8; ++w) sum += Acc[w][lane][wv];
      const int f = f0 + (lane & 31);
      const int t = t0 + 8 * wv + 4 * (lane >> 5);  // + r (contiguous)
      *(float4v*)(out + ((size_t)((2 * bp + bi) * 128 + f)) * 128 + t) = sum;
    }
  }
}

extern "C" void kernel_launch(void* const* d_in, const int* in_sizes, int n_in,
                              void* d_out, int out_size, void* d_ws, size_t ws_size,
                              hipStream_t stream) {
  const float* signal = (const float*)d_in[0];
  float* out = (float*)d_out;
  gabor_kernel<<<dim3(256), dim3(512), 0, stream>>>(signal, out);
}